// Round 6
// baseline (151.589 us; speedup 1.0000x reference)
//
#include <hip/hip_runtime.h>

constexpr int F = 2048;            // NUM_FEATURES
constexpr int NROWS = 8192;        // rows
constexpr float EPS = 1e-6f;
constexpr int S4 = F / 4;          // 512 float4 per row

// ---- Stage A grid: 8 colgroups x 256 rowgroups = 2048 blocks (8/CU) ----
// 32 waves/CU, 8 independent loads batched per thread -> BW-bound, not latency-bound.
constexpr int CG = 8;
constexpr int RG = 256;
constexpr int NB1 = CG * RG;
constexpr int RPT = 8;             // rows per thread; block covers 32 rows x 64 float4-cols

// ws layout (no zero-init needed -- every byte read later is written first):
//   pS: RG*S4 float4 (2 MB)  partial sums
//   pQ: RG*S4 float4 (2 MB)  partial sumsq
//   stats: 2F floats         (rstd, -mean*rstd)

using fx4 = __attribute__((ext_vector_type(4))) float;

// ---------------------------------------------------------------------------
// Stage A: per-block partial sum/sumsq -> plain float4 stores (NO atomics).
// ---------------------------------------------------------------------------
__global__ __launch_bounds__(256) void partial_kernel(const float* __restrict__ x,
                                                      float4* __restrict__ pS,
                                                      float4* __restrict__ pQ) {
    __shared__ float4 lS[3 * 64];
    __shared__ float4 lQ[3 * 64];

    const int tid = threadIdx.x;
    const int lc  = tid & 63;
    const int sg  = tid >> 6;
    const int cg  = blockIdx.x & (CG - 1);
    const int rg  = blockIdx.x >> 3;          // 0..255
    const int c4  = cg * 64 + lc;
    const int row0 = rg * 32 + sg * RPT;

    const float4* __restrict__ xv = reinterpret_cast<const float4*>(x);
    const size_t base = (size_t)row0 * S4 + (size_t)c4;

    // batch all 8 loads before any use -> 8 outstanding 1KB wave-loads
    float4 v[RPT];
#pragma unroll
    for (int r = 0; r < RPT; ++r) v[r] = xv[base + (size_t)r * S4];

    float4 s = make_float4(0.f, 0.f, 0.f, 0.f);
    float4 q = make_float4(0.f, 0.f, 0.f, 0.f);
#pragma unroll
    for (int r = 0; r < RPT; ++r) {
        s.x += v[r].x;  s.y += v[r].y;  s.z += v[r].z;  s.w += v[r].w;
        q.x += v[r].x * v[r].x;  q.y += v[r].y * v[r].y;
        q.z += v[r].z * v[r].z;  q.w += v[r].w * v[r].w;
    }

    if (sg != 0) {
        lS[(sg - 1) * 64 + lc] = s;
        lQ[(sg - 1) * 64 + lc] = q;
    }
    __syncthreads();
    if (sg == 0) {
#pragma unroll
        for (int k = 0; k < 3; ++k) {
            float4 t = lS[k * 64 + lc];
            float4 u = lQ[k * 64 + lc];
            s.x += t.x;  s.y += t.y;  s.z += t.z;  s.w += t.w;
            q.x += u.x;  q.y += u.y;  q.z += u.z;  q.w += u.w;
        }
        pS[(size_t)rg * S4 + c4] = s;   // plain stores -- no atomics, no fence
        pQ[(size_t)rg * S4 + c4] = q;
    }
}

// ---------------------------------------------------------------------------
// Stage B: sum 256 partials per scalar column, emit (rstd, -mean*rstd).
// 8 blocks x 256 threads; 4 MB of L2/L3-resident coalesced reads.
// ---------------------------------------------------------------------------
__global__ __launch_bounds__(256) void stats_kernel(const float* __restrict__ pS,
                                                    const float* __restrict__ pQ,
                                                    float* __restrict__ stats) {
    const int c = blockIdx.x * 256 + threadIdx.x;   // 0..F-1
    float s1 = 0.f, s2 = 0.f;
#pragma unroll 8
    for (int b = 0; b < RG; ++b) {
        s1 += pS[(size_t)b * F + c];
        s2 += pQ[(size_t)b * F + c];
    }
    const float mean = s1 * (1.0f / (float)NROWS);
    float var = (s2 - s1 * mean) * (1.0f / (float)(NROWS - 1));
    var = fmaxf(var, 0.0f);
    const float r = rsqrtf(var + EPS);
    stats[c]     = r;
    stats[c + F] = -mean * r;           // out = x*r + b
}

// ---------------------------------------------------------------------------
// Stage C: normalize. 4 float4/thread, one stats load (chunk stride is a
// multiple of the row length so all 4 share a column). NT stores for out.
// x is L3-warm from stage A -> reads mostly hit L3.
// ---------------------------------------------------------------------------
constexpr int NPT = 4;
constexpr int TOTAL4 = NROWS * S4;        // 4,194,304
constexpr int CHUNK = TOTAL4 / NPT;       // 1,048,576 (multiple of S4)

__global__ __launch_bounds__(256) void normalize_kernel(const float* __restrict__ x,
                                                        const float* __restrict__ stats,
                                                        float* __restrict__ out) {
    const int i = blockIdx.x * 256 + threadIdx.x;    // 0 .. CHUNK-1
    const int c4 = i & (S4 - 1);
    const float4* __restrict__ xv = reinterpret_cast<const float4*>(x);
    fx4* __restrict__ ov          = reinterpret_cast<fx4*>(out);
    const float4 r = reinterpret_cast<const float4*>(stats)[c4];
    const float4 b = reinterpret_cast<const float4*>(stats + F)[c4];

    float4 v[NPT];
#pragma unroll
    for (int k = 0; k < NPT; ++k) {
        v[k] = xv[(size_t)i + (size_t)k * CHUNK];
    }
#pragma unroll
    for (int k = 0; k < NPT; ++k) {
        fx4 o;
        o.x = fmaf(v[k].x, r.x, b.x);
        o.y = fmaf(v[k].y, r.y, b.y);
        o.z = fmaf(v[k].z, r.z, b.z);
        o.w = fmaf(v[k].w, r.w, b.w);
        __builtin_nontemporal_store(o, &ov[(size_t)i + (size_t)k * CHUNK]);
    }
}

extern "C" void kernel_launch(void* const* d_in, const int* in_sizes, int n_in,
                              void* d_out, int out_size, void* d_ws, size_t ws_size,
                              hipStream_t stream) {
    const float* x = (const float*)d_in[0];
    // running_mean / running_var are wiped by the Welford recurrence (n=1 / n=2).
    float* out = (float*)d_out;

    float4* pS    = (float4*)d_ws;
    float4* pQ    = pS + (size_t)RG * S4;
    float*  stats = (float*)(pQ + (size_t)RG * S4);

    // No memset: every ws byte consumed downstream is produced by stage A/B first.
    partial_kernel<<<NB1, 256, 0, stream>>>(x, pS, pQ);
    stats_kernel<<<F / 256, 256, 0, stream>>>((const float*)pS, (const float*)pQ, stats);
    normalize_kernel<<<CHUNK / 256, 256, 0, stream>>>(x, stats, out);
}